// Round 6
// baseline (687.480 us; speedup 1.0000x reference)
//
#include <hip/hip_runtime.h>
#include <hip/hip_cooperative_groups.h>
#include <hip/hip_bf16.h>

namespace cg = cooperative_groups;

constexpr int N_NODES = 20000;
constexpr int N_EDGES = 50000;
constexpr int IN_DIM  = 512;
constexpr int D       = 32;

typedef float vf4 __attribute__((ext_vector_type(4)));

// ws layout (4-byte words): deg int[20480] | sumc f[20480] | Bacc f[640000]
//                           | A f[640000] | B f[640000]
constexpr int OFF_DEG  = 0;
constexpr int OFF_SUMC = 20480;
constexpr int OFF_BACC = 40960;
constexpr int OFF_A    = 40960 + 640000;     // 680960
constexpr int OFF_B    = OFF_A + 640000;     // 1320960
constexpr int ZERO_WORDS = OFF_BACC + 640000; // deg+sumc+Bacc contiguous

struct KArgs {
    const float* x; const int* ei;
    const float* W; const float* b;
    const float* alpha0; const float* T0; const float* rw0; const float* g0; const float* be0;
    const float* alpha1; const float* T1; const float* rw1; const float* g1; const float* be1;
    float* out; int* wsi; float* wsf;
};

__device__ __forceinline__ float dot4(vf4 a, vf4 b) {
    return fmaf(a.x, b.x, fmaf(a.y, b.y, fmaf(a.z, b.z, a.w * b.w)));
}

// ---------------------------------------------------------------------------
__device__ __forceinline__ void d_zero(int* wsi, int gtid, int nth) {
    for (int i = gtid; i < ZERO_WORDS; i += nth) wsi[i] = 0;
}

__device__ __forceinline__ void d_deg(const int* __restrict__ ei, int* __restrict__ deg,
                                      int gtid, int nth) {
    for (int i = gtid; i < 2 * N_EDGES; i += nth) atomicAdd(&deg[ei[i]], 1);
}

__device__ __forceinline__ void d_proj(const float* __restrict__ x, const float* __restrict__ W,
                                       const float* __restrict__ bias, float* __restrict__ A,
                                       float (*xs)[IN_DIM]) {
    const int tid = threadIdx.x;
    const int r = tid >> 5, c = tid & 31;
    for (int grp = blockIdx.x; grp < N_NODES / 8; grp += gridDim.x) {
        const vf4* xsrc = (const vf4*)(x + (size_t)grp * 8 * IN_DIM);
        vf4* xdst = (vf4*)&xs[0][0];
        __syncthreads();                       // previous iteration's readers done
        #pragma unroll
        for (int i = 0; i < 4; ++i) xdst[tid + 256 * i] = xsrc[tid + 256 * i];
        __syncthreads();
        const float* xr = xs[r];
        float acc = bias[c];
        #pragma unroll 4
        for (int k = 0; k < IN_DIM; k += 4) {
            acc = fmaf(xr[k + 0], W[(k + 0) * D + c], acc);
            acc = fmaf(xr[k + 1], W[(k + 1) * D + c], acc);
            acc = fmaf(xr[k + 2], W[(k + 2) * D + c], acc);
            acc = fmaf(xr[k + 3], W[(k + 3) * D + c], acc);
        }
        A[(size_t)(grp * 8 + r) * D + c] = fmaxf(acc, 0.0f);
    }
}

// Edge phase: wave wv handles pair-units [wv*E/nwv, (wv+1)*E/nwv); unit u =
// transports 2u, 2u+1 (8 KB of T, contiguous per wave). Atomic scatter into
// Bacc/sumc (R2-proven body). Row of T element block: m*8+g trick avoids any
// post-reduce shuffle for the atomic path.
__device__ __forceinline__ void d_edge(const float* __restrict__ T, const float* __restrict__ rw,
                                       const float* __restrict__ alpha_p,
                                       const int* __restrict__ src, const int* __restrict__ dst,
                                       const int* __restrict__ deg, const float* __restrict__ h,
                                       float* __restrict__ Bacc, float* __restrict__ sumc,
                                       int wv, int nwv) {
    const int lane = threadIdx.x & 63;
    const int g = lane >> 3;   // row-group 0..7
    const int m = lane & 7;    // k-chunk  0..7
    const float alpha = alpha_p[0];
    const int lo = (int)(((long long)wv * N_EDGES) / nwv);
    const int hi = (int)(((long long)(wv + 1) * N_EDGES) / nwv);

    #pragma unroll 1
    for (int u = lo; u < hi; ++u) {
        const int t0 = 2 * u, t1 = t0 + 1;
        const int e0 = (t0 < N_EDGES) ? t0 : t0 - N_EDGES;
        const int e1 = (t1 < N_EDGES) ? t1 : t1 - N_EDGES;
        int in0, out0, in1, out1;
        if (t0 < N_EDGES) { in0 = src[e0]; out0 = dst[e0]; }
        else              { in0 = dst[e0]; out0 = src[e0]; }
        if (t1 < N_EDGES) { in1 = src[e1]; out1 = dst[e1]; }
        else              { in1 = dst[e1]; out1 = src[e1]; }

        const vf4* Tp = (const vf4*)(T + (size_t)t0 * (D * D));   // t1 tile follows contiguously
        vf4 a00 = Tp[lane],       a01 = Tp[64 + lane],  a02 = Tp[128 + lane], a03 = Tp[192 + lane];
        vf4 a10 = Tp[256 + lane], a11 = Tp[320 + lane], a12 = Tp[384 + lane], a13 = Tp[448 + lane];
        vf4 h0 = ((const vf4*)(h + (size_t)in0 * D))[m];
        vf4 h1 = ((const vf4*)(h + (size_t)in1 * D))[m];

        const float c0 = alpha * log1pf(expf(rw[t0])) / fmaxf((float)deg[out0], 1.0f);
        const float c1 = alpha * log1pf(expf(rw[t1])) / fmaxf((float)deg[out1], 1.0f);

        float p00 = dot4(a00, h0), p01 = dot4(a01, h0), p02 = dot4(a02, h0), p03 = dot4(a03, h0);
        float p10 = dot4(a10, h1), p11 = dot4(a11, h1), p12 = dot4(a12, h1), p13 = dot4(a13, h1);

        #define RED8(p) { p += __shfl_xor(p, 1); p += __shfl_xor(p, 2); p += __shfl_xor(p, 4); }
        RED8(p00) RED8(p01) RED8(p02) RED8(p03)
        RED8(p10) RED8(p11) RED8(p12) RED8(p13)
        #undef RED8

        if (m < 4) {
            const float v0 = (m == 0) ? p00 : (m == 1) ? p01 : (m == 2) ? p02 : p03;
            const float v1 = (m == 0) ? p10 : (m == 1) ? p11 : (m == 2) ? p12 : p13;
            const int row = m * 8 + g;
            atomicAdd(&Bacc[(size_t)out0 * D + row], c0 * v0);
            atomicAdd(&Bacc[(size_t)out1 * D + row], c1 * v1);
        }
        if (lane == 0)  atomicAdd(&sumc[out0], c0);
        if (lane == 32) atomicAdd(&sumc[out1], c1);
    }
}

__device__ __forceinline__ void d_ln(const float* __restrict__ h, float* __restrict__ Bacc,
                                     float* __restrict__ sumc, const float* __restrict__ gam,
                                     const float* __restrict__ bet, float* __restrict__ dest,
                                     bool rezero, int gtid, int nth) {
    const int c = threadIdx.x & 31;
    const int nrows = nth >> 5;
    for (int row = gtid >> 5; row < N_NODES; row += nrows) {
        const size_t idx = (size_t)row * D + c;
        const float sc = sumc[row];
        const float v  = h[idx] * (1.0f - sc) + Bacc[idx];

        float s = v;
        #pragma unroll
        for (int msk = 16; msk >= 1; msk >>= 1) s += __shfl_xor(s, msk);
        const float mu = s * (1.0f / 32.0f);
        const float dv = v - mu;
        float q = dv * dv;
        #pragma unroll
        for (int msk = 16; msk >= 1; msk >>= 1) q += __shfl_xor(q, msk);
        const float var = q * (1.0f / 32.0f);

        dest[idx] = fmaxf(dv * rsqrtf(var + 1e-5f) * gam[c] + bet[c], 0.0f);
        if (rezero) {
            Bacc[idx] = 0.0f;
            if (c == 0) sumc[row] = 0.0f;
        }
    }
}

// ---------------------------------------------------------------------------
// Single cooperative kernel: zero | proj+deg | edge0 | ln0 | edge1 | ln1
__global__ __launch_bounds__(256, 4) void k_all(KArgs p) {
    cg::grid_group grid = cg::this_grid();
    __shared__ float xs[8][IN_DIM];
    const int gtid = blockIdx.x * 256 + threadIdx.x;
    const int nth  = gridDim.x * 256;
    const int wv   = __builtin_amdgcn_readfirstlane(gtid >> 6);
    const int nwv  = nth >> 6;

    int*   deg  = p.wsi + OFF_DEG;
    float* sumc = p.wsf + OFF_SUMC;
    float* Bacc = p.wsf + OFF_BACC;
    float* A    = p.wsf + OFF_A;
    float* Bh   = p.wsf + OFF_B;
    const int* src = p.ei;
    const int* dst = p.ei + N_EDGES;

    d_zero(p.wsi, gtid, nth);
    grid.sync();

    d_deg(p.ei, deg, gtid, nth);
    d_proj(p.x, p.W, p.b, A, xs);
    grid.sync();

    d_edge(p.T0, p.rw0, p.alpha0, src, dst, deg, A, Bacc, sumc, wv, nwv);
    grid.sync();

    d_ln(A, Bacc, sumc, p.g0, p.be0, Bh, true, gtid, nth);
    grid.sync();

    d_edge(p.T1, p.rw1, p.alpha1, src, dst, deg, Bh, Bacc, sumc, wv, nwv);
    grid.sync();

    d_ln(Bh, Bacc, sumc, p.g1, p.be1, p.out, false, gtid, nth);
}

// ---------------------------------------------------------------------------
// Fallback path (plain dispatches) in case cooperative launch is rejected.
__global__ __launch_bounds__(256) void k_zero_f(KArgs p) {
    d_zero(p.wsi, blockIdx.x * 256 + threadIdx.x, gridDim.x * 256);
}
__global__ __launch_bounds__(256, 4) void k_projdeg_f(KArgs p) {
    __shared__ float xs[8][IN_DIM];
    const int gtid = blockIdx.x * 256 + threadIdx.x;
    d_deg(p.ei, p.wsi + OFF_DEG, gtid, gridDim.x * 256);
    d_proj(p.x, p.W, p.b, p.wsf + OFF_A, xs);
}
__global__ __launch_bounds__(256, 4) void k_edge_f(KArgs p, int layer) {
    const int gtid = blockIdx.x * 256 + threadIdx.x;
    const int wv   = __builtin_amdgcn_readfirstlane(gtid >> 6);
    const int nwv  = (gridDim.x * 256) >> 6;
    const float* h = (layer == 0) ? p.wsf + OFF_A : p.wsf + OFF_B;
    d_edge(layer == 0 ? p.T0 : p.T1, layer == 0 ? p.rw0 : p.rw1,
           layer == 0 ? p.alpha0 : p.alpha1, p.ei, p.ei + N_EDGES,
           p.wsi + OFF_DEG, h, p.wsf + OFF_BACC, p.wsf + OFF_SUMC, wv, nwv);
}
__global__ __launch_bounds__(256, 4) void k_ln_f(KArgs p, int layer) {
    const int gtid = blockIdx.x * 256 + threadIdx.x;
    if (layer == 0)
        d_ln(p.wsf + OFF_A, p.wsf + OFF_BACC, p.wsf + OFF_SUMC, p.g0, p.be0,
             p.wsf + OFF_B, true, gtid, gridDim.x * 256);
    else
        d_ln(p.wsf + OFF_B, p.wsf + OFF_BACC, p.wsf + OFF_SUMC, p.g1, p.be1,
             p.out, false, gtid, gridDim.x * 256);
}

// ---------------------------------------------------------------------------
extern "C" void kernel_launch(void* const* d_in, const int* in_sizes, int n_in,
                              void* d_out, int out_size, void* d_ws, size_t ws_size,
                              hipStream_t stream) {
    KArgs ka;
    ka.x      = (const float*)d_in[0];
    ka.ei     = (const int*)  d_in[1];
    ka.W      = (const float*)d_in[2];
    ka.b      = (const float*)d_in[3];
    ka.alpha0 = (const float*)d_in[4];
    ka.T0     = (const float*)d_in[5];
    ka.rw0    = (const float*)d_in[6];
    ka.g0     = (const float*)d_in[7];
    ka.be0    = (const float*)d_in[8];
    ka.alpha1 = (const float*)d_in[9];
    ka.T1     = (const float*)d_in[10];
    ka.rw1    = (const float*)d_in[11];
    ka.g1     = (const float*)d_in[12];
    ka.be1    = (const float*)d_in[13];
    ka.out    = (float*)d_out;
    ka.wsi    = (int*)d_ws;
    ka.wsf    = (float*)d_ws;

    int occ = 0;
    hipError_t qerr = hipOccupancyMaxActiveBlocksPerMultiprocessor(&occ, k_all, 256, 0);
    if (qerr != hipSuccess || occ <= 0) occ = 2;
    if (occ > 8) occ = 8;
    const int grid = occ * 256;   // 256 CUs on MI355X; all phases are grid-stride

    void* args[] = { (void*)&ka };
    hipError_t lerr = hipLaunchCooperativeKernel((const void*)k_all, dim3(grid), dim3(256),
                                                 args, 0, stream);
    if (lerr != hipSuccess) {
        // fallback: plain dispatch sequence (R2-equivalent)
        k_zero_f   <<<2048, 256, 0, stream>>>(ka);
        k_projdeg_f<<<1024, 256, 0, stream>>>(ka);
        k_edge_f   <<<1024, 256, 0, stream>>>(ka, 0);
        k_ln_f     <<<1024, 256, 0, stream>>>(ka, 0);
        k_edge_f   <<<1024, 256, 0, stream>>>(ka, 1);
        k_ln_f     <<<1024, 256, 0, stream>>>(ka, 1);
    }
}

// Round 7
// 225.527 us; speedup vs baseline: 3.0483x; 3.0483x over previous
//
#include <hip/hip_runtime.h>
#include <hip/hip_bf16.h>

constexpr int N_NODES = 20000;
constexpr int N_EDGES = 50000;
constexpr int IN_DIM  = 512;
constexpr int D       = 32;

typedef float vf4 __attribute__((ext_vector_type(4)));

// ws layout (floats): deg int[20480] | sumc f[20480] | Bacc f[640000] | A f[640000]
constexpr size_t OFF_DEG  = 0;
constexpr size_t OFF_SUMC = 20480;
constexpr size_t OFF_BACC = 40960;
constexpr size_t OFF_A    = 680960;

__device__ __forceinline__ float dot4(vf4 a, vf4 b) {
    return fmaf(a.x, b.x, fmaf(a.y, b.y, fmaf(a.z, b.z, a.w * b.w)));
}

// ---------------------------------------------------------------------------
// h = relu(x @ W + b) -> A ; fused integer degree histogram (40 slots/block)
__global__ __launch_bounds__(256) void k_proj(const float* __restrict__ x,
                                              const float* __restrict__ W,
                                              const float* __restrict__ b,
                                              const int* __restrict__ ei,
                                              float* __restrict__ A,
                                              int* __restrict__ deg) {
    __shared__ float xs[8][IN_DIM];
    const int tid  = threadIdx.x;
    const int row0 = blockIdx.x * 8;

    if (tid < 40) atomicAdd(&deg[ei[blockIdx.x * 40 + tid]], 1);

    const vf4* xsrc = (const vf4*)(x + (size_t)row0 * IN_DIM);
    vf4* xdst = (vf4*)&xs[0][0];
    #pragma unroll
    for (int i = 0; i < 4; ++i) xdst[tid + 256 * i] = xsrc[tid + 256 * i];
    __syncthreads();

    const int r = tid >> 5;
    const int c = tid & 31;
    const float* xr = xs[r];
    float acc = b[c];
    #pragma unroll 4
    for (int k = 0; k < IN_DIM; k += 4) {
        acc = fmaf(xr[k + 0], W[(k + 0) * D + c], acc);
        acc = fmaf(xr[k + 1], W[(k + 1) * D + c], acc);
        acc = fmaf(xr[k + 2], W[(k + 2) * D + c], acc);
        acc = fmaf(xr[k + 3], W[(k + 3) * D + c], acc);
    }
    A[(size_t)(row0 + r) * D + c] = fmaxf(acc, 0.0f);
}

// ---------------------------------------------------------------------------
// One wave per FOUR transports (unit u = t0..t0+3, 16 KB contiguous T).
// y = T[t] @ h[in]; Bacc[out] += c*y (atomics); sumc[out] += c.
// T load: instr j, lane l -> contiguous elem j*256+l*4; row (l&7)*8+(l>>3)... i.e.
// after RED8 over the 8-lane k-group, row m*8+g lives at lanes with (g=l>>3,m=l&7).
__global__ __launch_bounds__(256) void k_edge(const float* __restrict__ T,
                                              const float* __restrict__ rw,
                                              const float* __restrict__ alpha_p,
                                              const int* __restrict__ src,
                                              const int* __restrict__ dst,
                                              const int* __restrict__ deg,
                                              const float* __restrict__ hA,
                                              float* __restrict__ Bacc,
                                              float* __restrict__ sumc) {
    const int wave = (blockIdx.x * 256 + threadIdx.x) >> 6;
    const int lane = threadIdx.x & 63;
    const int t0 = wave * 4;

    const int g = lane >> 3;   // row-group 0..7
    const int m = lane & 7;    // k-chunk  0..7

    // ---- scalar-ish loads first (ei / rw / deg), then h, then the T stream
    int in[4], out[4];
    #pragma unroll
    for (int q = 0; q < 4; ++q) {
        const int t = t0 + q;
        const int e = (t < N_EDGES) ? t : t - N_EDGES;
        if (t < N_EDGES) { in[q] = src[e]; out[q] = dst[e]; }
        else             { in[q] = dst[e]; out[q] = src[e]; }
    }
    const float alpha = alpha_p[0];
    float c_[4];
    #pragma unroll
    for (int q = 0; q < 4; ++q)
        c_[q] = alpha * log1pf(expf(rw[t0 + q])) / fmaxf((float)deg[out[q]], 1.0f);

    vf4 hv[4];
    #pragma unroll
    for (int q = 0; q < 4; ++q)
        hv[q] = ((const vf4*)(hA + (size_t)in[q] * D))[m];

    const vf4* Tp = (const vf4*)(T + (size_t)t0 * (D * D));   // 16 KB contiguous
    vf4 a0  = Tp[lane],        a1  = Tp[64 + lane],  a2  = Tp[128 + lane], a3  = Tp[192 + lane];
    vf4 a4  = Tp[256 + lane],  a5  = Tp[320 + lane], a6  = Tp[384 + lane], a7  = Tp[448 + lane];
    vf4 a8  = Tp[512 + lane],  a9  = Tp[576 + lane], a10 = Tp[640 + lane], a11 = Tp[704 + lane];
    vf4 a12 = Tp[768 + lane],  a13 = Tp[832 + lane], a14 = Tp[896 + lane], a15 = Tp[960 + lane];

    #define RED8(p) { p += __shfl_xor(p, 1); p += __shfl_xor(p, 2); p += __shfl_xor(p, 4); }
    #define DO_T(q, b0, b1, b2, b3)                                                 \
    {                                                                                \
        float p0 = dot4(b0, hv[q]), p1 = dot4(b1, hv[q]),                            \
              p2 = dot4(b2, hv[q]), p3 = dot4(b3, hv[q]);                            \
        RED8(p0) RED8(p1) RED8(p2) RED8(p3)                                          \
        if (m < 4) {                                                                 \
            const float v = (m == 0) ? p0 : (m == 1) ? p1 : (m == 2) ? p2 : p3;      \
            atomicAdd(&Bacc[(size_t)out[q] * D + (m * 8 + g)], c_[q] * v);           \
        }                                                                            \
        if (lane == (q & 1) * 32 + (q >> 1))                                         \
            atomicAdd(&sumc[out[q]], c_[q]);                                         \
    }
    DO_T(0, a0,  a1,  a2,  a3)
    DO_T(1, a4,  a5,  a6,  a7)
    DO_T(2, a8,  a9,  a10, a11)
    DO_T(3, a12, a13, a14, a15)
    #undef DO_T
    #undef RED8
}

// ---------------------------------------------------------------------------
// h_pre = h*(1-sumc) + Bacc ; y = relu(layernorm(h_pre)) -> dest
// If do_zero: re-zero Bacc/sumc for the next layer.
__global__ __launch_bounds__(256) void k_ln(const float* __restrict__ h,
                                            float* __restrict__ Bacc,
                                            float* __restrict__ sumc,
                                            const float* __restrict__ gam,
                                            const float* __restrict__ bet,
                                            float* __restrict__ dest,
                                            int do_zero) {
    const int tid = threadIdx.x;
    const int row = blockIdx.x * 8 + (tid >> 5);
    const int c   = tid & 31;
    const size_t idx = (size_t)row * D + c;

    const float sc = sumc[row];
    const float v  = h[idx] * (1.0f - sc) + Bacc[idx];

    float s = v;
    #pragma unroll
    for (int msk = 16; msk >= 1; msk >>= 1) s += __shfl_xor(s, msk);
    const float mu = s * (1.0f / 32.0f);
    const float dv = v - mu;
    float q = dv * dv;
    #pragma unroll
    for (int msk = 16; msk >= 1; msk >>= 1) q += __shfl_xor(q, msk);
    const float var = q * (1.0f / 32.0f);

    float y = dv * rsqrtf(var + 1e-5f) * gam[c] + bet[c];
    dest[idx] = fmaxf(y, 0.0f);

    if (do_zero) {
        Bacc[idx] = 0.0f;
        if (c == 0) sumc[row] = 0.0f;
    }
}

// ---------------------------------------------------------------------------
extern "C" void kernel_launch(void* const* d_in, const int* in_sizes, int n_in,
                              void* d_out, int out_size, void* d_ws, size_t ws_size,
                              hipStream_t stream) {
    const float* x      = (const float*)d_in[0];
    const int*   ei     = (const int*)  d_in[1];   // [2, E]: src row | dst row
    const float* W      = (const float*)d_in[2];
    const float* b      = (const float*)d_in[3];
    const float* alpha0 = (const float*)d_in[4];
    const float* T0     = (const float*)d_in[5];
    const float* rw0    = (const float*)d_in[6];
    const float* g0     = (const float*)d_in[7];
    const float* be0    = (const float*)d_in[8];
    const float* alpha1 = (const float*)d_in[9];
    const float* T1     = (const float*)d_in[10];
    const float* rw1    = (const float*)d_in[11];
    const float* g1     = (const float*)d_in[12];
    const float* be1    = (const float*)d_in[13];

    float* out = (float*)d_out;
    int*   wsi = (int*)d_ws;
    float* wsf = (float*)d_ws;

    int*   deg  = wsi + OFF_DEG;
    float* sumc = wsf + OFF_SUMC;
    float* Bacc = wsf + OFF_BACC;
    float* A    = wsf + OFF_A;

    const int* src = ei;
    const int* dst = ei + N_EDGES;

    // zero deg + sumc + Bacc in one memset
    (void)hipMemsetAsync(wsi, 0, OFF_A * sizeof(float), stream);

    k_proj<<<N_NODES / 8, 256, 0, stream>>>(x, W, b, ei, A, deg);

    const int edge_blocks = (2 * N_EDGES) / 16;   // 4 transports/wave, 4 waves/block
    k_edge<<<edge_blocks, 256, 0, stream>>>(T0, rw0, alpha0, src, dst, deg, A, Bacc, sumc);
    k_ln<<<N_NODES / 8, 256, 0, stream>>>(A, Bacc, sumc, g0, be0, A, 1);

    k_edge<<<edge_blocks, 256, 0, stream>>>(T1, rw1, alpha1, src, dst, deg, A, Bacc, sumc);
    k_ln<<<N_NODES / 8, 256, 0, stream>>>(A, Bacc, sumc, g1, be1, out, 0);
}